// Round 11
// baseline (60.030 us; speedup 1.0000x reference)
//
#include <hip/hip_runtime.h>
#include <math.h>

#define TSAMP 30
#define RPB   1024       // pairs per block (contiguous range)
#define ITERS (RPB / 256)
#define FEPS  1e-15f

// softplus(x) = log1p(exp(x)), stable, 1 exp + 1 log
__device__ __forceinline__ float softplus(float x) {
    return fmaxf(x, 0.0f) + __logf(1.0f + __expf(-fabsf(x)));
}

// Kernel 1 — FROZEN from R10 (50.9 us total, ~5.8 TB/s effective).
// Linear-stream layout: each block owns ONE t-row over a contiguous 1024-pair
// range -> noise reads are a single linear stream per block. Params re-read per
// (t, range) are served by XCD-local L2 (bid%8 co-location swizzle).
// R5/R6/R8 lesson: no fused ticket/__threadfence epilogue (150 GB/s collapse).
__global__ __launch_bounds__(256) void bcc_partial(
    const float4* __restrict__ logit4,   // [npair]
    const float2* __restrict__ var2,     // [npair]
    const int2*   __restrict__ true2,    // [npair]
    const float4* __restrict__ noise4,   // [TSAMP][npair]
    float* __restrict__ partial,         // [32][npr]
    int npair, int npr)
{
    int t, pr;
    if ((npr & 7) == 0) {
        // XCD co-location: bid%8 = XCD (dispatch round-robin heuristic)
        const int x    = blockIdx.x & 7;
        const int slot = blockIdx.x >> 3;
        t  = slot % TSAMP;
        pr = x * (npr >> 3) + slot / TSAMP;
    } else {
        t  = blockIdx.x % TSAMP;
        pr = blockIdx.x / TSAMP;
    }

    const float4* nrow = noise4 + (size_t)t * (size_t)npair;
    const int base = pr * RPB;

    float acc = 0.0f, u_acc = 0.0f, vd_acc = 0.0f;

    #pragma unroll
    for (int it = 0; it < ITERS; ++it) {
        const int p = base + it * 256 + (int)threadIdx.x;
        if (p < npair) {
            const float4 nz = nrow[p];
            const float4 lg = logit4[p];
            const float2 v  = var2[p];
            const int2   yy = true2[p];

            const float sg0 = yy.x ? 1.0f : -1.0f;
            const float d0  = sg0 * (lg.x - lg.y);
            const float ss0 = sg0 * (__fsqrt_rn(v.x) + FEPS);
            const float sg1 = yy.y ? 1.0f : -1.0f;
            const float d1  = sg1 * (lg.z - lg.w);
            const float ss1 = sg1 * (__fsqrt_rn(v.y) + FEPS);

            acc -= softplus(fmaf(ss0, nz.x - nz.y, d0))
                 + softplus(fmaf(ss1, nz.z - nz.w, d1));

            if (t == 0) {   // block-uniform branch
                vd_acc += (__expf(v.x) - 1.0f) + (__expf(v.y) - 1.0f);
                u_acc  -= softplus(d0) + softplus(d1);
            }
        }
    }

    // block-reduce 3 slots (deterministic)
    __shared__ float s_part[4][3];
    const int lane = threadIdx.x & 63;
    const int wav  = threadIdx.x >> 6;
    #pragma unroll
    for (int a = 0; a < 3; ++a) {
        float vv = (a == 0) ? acc : ((a == 1) ? u_acc : vd_acc);
        #pragma unroll
        for (int off = 32; off >= 1; off >>= 1)
            vv += __shfl_down(vv, off, 64);
        if (lane == 0) s_part[wav][a] = vv;
    }
    __syncthreads();
    if (threadIdx.x == 0) {
        const float s0 = s_part[0][0] + s_part[1][0] + s_part[2][0] + s_part[3][0];
        partial[(size_t)t * (size_t)npr + pr] = s0;
        if (t == 0) {
            const float s1 = s_part[0][1] + s_part[1][1] + s_part[2][1] + s_part[3][1];
            const float s2 = s_part[0][2] + s_part[1][2] + s_part[2][2] + s_part[3][2];
            partial[(size_t)30 * (size_t)npr + pr] = s1;
            partial[(size_t)31 * (size_t)npr + pr] = s2;
        }
    }
}

// Kernel 2 (merged reduce + epilogue): ONE block, 1024 threads.
// slot a = tid>>5 (0..31), 32 lanes per slot; float4 row reads -> each lane
// issues npr/128 independent loads (one pipelined latency round-trip);
// 32-wide in-wave shfl reduce; thread 0 runs the scalar epilogue.
__global__ __launch_bounds__(1024) void bcc_finish(
    const float* __restrict__ partial,   // [32][npr]
    int npr, float invN, float* __restrict__ out)
{
    const int a = threadIdx.x >> 5;          // slot 0..31
    const int j = threadIdx.x & 31;          // lane within slot
    const float* row = partial + (size_t)a * (size_t)npr;
    float s = 0.0f;
    const int nv = npr >> 2;
    const float4* row4 = (const float4*)row;
    for (int q = j; q < nv; q += 32) {
        const float4 vv = row4[q];
        s += (vv.x + vv.y) + (vv.z + vv.w);
    }
    for (int q = (nv << 2) + j; q < npr; q += 32)
        s += row[q];
    #pragma unroll
    for (int off = 16; off >= 1; off >>= 1)
        s += __shfl_down(s, off, 32);
    __shared__ float res[32];
    if (j == 0) res[a] = s;
    __syncthreads();
    if (threadIdx.x == 0) {
        const float U  = -res[30] * invN;          // undistorted_loss
        const float vd =  res[31] * invN;          // mean variance_depressor
        float mc_sum = 0.0f;
        #pragma unroll
        for (int t = 0; t < TSAMP; ++t) {
            const float D = -res[t] * invN;        // distorted_loss[t]
            const float x = U - D;
            const float e = (x > 0.0f) ? x : expm1f(x);   // elu(x)
            mc_sum += -e;                           // monte_carlo[t]
        }
        const float variance_loss = (mc_sum / (float)TSAMP) * U;
        out[0] = variance_loss + U + vd;
    }
}

extern "C" void kernel_launch(void* const* d_in, const int* in_sizes, int n_in,
                              void* d_out, int out_size, void* d_ws, size_t ws_size,
                              hipStream_t stream) {
    const float* logit = (const float*)d_in[0];   // [N,2] f32
    const float* var   = (const float*)d_in[1];   // [N,1] f32
    const int*   tru   = (const int*)d_in[2];     // [N]   i32
    const float* noise = (const float*)d_in[3];   // [30,N,2] f32
    float* out = (float*)d_out;

    const int N = in_sizes[1];          // var has N elements
    const int npair = N / 2;

    int npr = (npair + RPB - 1) / RPB;  // 512 for N=1M
    {
        const size_t need = (size_t)32 * (size_t)npr * sizeof(float);
        if (ws_size < need) {
            npr = (int)(ws_size / (32 * sizeof(float)));
            if (npr < 1) npr = 1;
        }
    }
    float* partial = (float*)d_ws;      // [32][npr]

    bcc_partial<<<TSAMP * npr, 256, 0, stream>>>(
        (const float4*)logit, (const float2*)var, (const int2*)tru,
        (const float4*)noise, partial, npair, npr);

    bcc_finish<<<1, 1024, 0, stream>>>(partial, npr, 1.0f / (float)N, out);
}

// Round 12
// 56.441 us; speedup vs baseline: 1.0636x; 1.0636x over previous
//
#include <hip/hip_runtime.h>
#include <math.h>

#define TSAMP 30
#define RPB   2048       // pairs per block (contiguous range)
#define ITERS (RPB / 256)
#define FEPS  1e-15f

// softplus(x) = log1p(exp(x)), stable, 1 exp + 1 log
__device__ __forceinline__ float softplus(float x) {
    return fmaxf(x, 0.0f) + __logf(1.0f + __expf(-fabsf(x)));
}

// Kernel 1 — R10 linear-stream layout (50.9 us total, ~5.8 TB/s effective).
// Each block owns ONE t-row over a contiguous RPB-pair range -> noise reads are
// a single linear stream per block. Params re-read per (t, range) served by
// XCD-local L2 (bid%8 co-location swizzle).
// Lessons baked in: no fused ticket/__threadfence epilogue (R5/R6/R8: 150 GB/s
// collapse); no single-block final reduce (R11: +9 us, cross-XCD latency on 1 CU).
__global__ __launch_bounds__(256) void bcc_partial(
    const float4* __restrict__ logit4,   // [npair]
    const float2* __restrict__ var2,     // [npair]
    const int2*   __restrict__ true2,    // [npair]
    const float4* __restrict__ noise4,   // [TSAMP][npair]
    float* __restrict__ partial,         // [32][npr]
    int npair, int npr)
{
    int t, pr;
    if ((npr & 7) == 0) {
        // XCD co-location: bid%8 = XCD (dispatch round-robin heuristic)
        const int x    = blockIdx.x & 7;
        const int slot = blockIdx.x >> 3;
        t  = slot % TSAMP;
        pr = x * (npr >> 3) + slot / TSAMP;
    } else {
        t  = blockIdx.x % TSAMP;
        pr = blockIdx.x / TSAMP;
    }

    const float4* nrow = noise4 + (size_t)t * (size_t)npair;
    const int base = pr * RPB;

    float acc = 0.0f, u_acc = 0.0f, vd_acc = 0.0f;

    #pragma unroll
    for (int it = 0; it < ITERS; ++it) {
        const int p = base + it * 256 + (int)threadIdx.x;
        if (p < npair) {
            const float4 nz = nrow[p];
            const float4 lg = logit4[p];
            const float2 v  = var2[p];
            const int2   yy = true2[p];

            const float sg0 = yy.x ? 1.0f : -1.0f;
            const float d0  = sg0 * (lg.x - lg.y);
            const float ss0 = sg0 * (__fsqrt_rn(v.x) + FEPS);
            const float sg1 = yy.y ? 1.0f : -1.0f;
            const float d1  = sg1 * (lg.z - lg.w);
            const float ss1 = sg1 * (__fsqrt_rn(v.y) + FEPS);

            acc -= softplus(fmaf(ss0, nz.x - nz.y, d0))
                 + softplus(fmaf(ss1, nz.z - nz.w, d1));

            if (t == 0) {   // block-uniform branch
                vd_acc += (__expf(v.x) - 1.0f) + (__expf(v.y) - 1.0f);
                u_acc  -= softplus(d0) + softplus(d1);
            }
        }
    }

    // block-reduce 3 slots (deterministic)
    __shared__ float s_part[4][3];
    const int lane = threadIdx.x & 63;
    const int wav  = threadIdx.x >> 6;
    #pragma unroll
    for (int a = 0; a < 3; ++a) {
        float vv = (a == 0) ? acc : ((a == 1) ? u_acc : vd_acc);
        #pragma unroll
        for (int off = 32; off >= 1; off >>= 1)
            vv += __shfl_down(vv, off, 64);
        if (lane == 0) s_part[wav][a] = vv;
    }
    __syncthreads();
    if (threadIdx.x == 0) {
        const float s0 = s_part[0][0] + s_part[1][0] + s_part[2][0] + s_part[3][0];
        partial[(size_t)t * (size_t)npr + pr] = s0;
        if (t == 0) {
            const float s1 = s_part[0][1] + s_part[1][1] + s_part[2][1] + s_part[3][1];
            const float s2 = s_part[0][2] + s_part[1][2] + s_part[2][2] + s_part[3][2];
            partial[(size_t)30 * (size_t)npr + pr] = s1;
            partial[(size_t)31 * (size_t)npr + pr] = s2;
        }
    }
}

// Kernel 2: 32 blocks, block a reduces partial[a][0..npr) -> res32[a].
__global__ __launch_bounds__(256) void bcc_reduce(
    const float* __restrict__ partial,   // [32][npr]
    int npr, float* __restrict__ res32)  // [32]
{
    const int a = blockIdx.x;
    const float* row = partial + (size_t)a * (size_t)npr;
    float s = 0.0f;
    for (int j = threadIdx.x; j < npr; j += 256)
        s += row[j];
    #pragma unroll
    for (int off = 32; off >= 1; off >>= 1)
        s += __shfl_down(s, off, 64);
    __shared__ float sw[4];
    if ((threadIdx.x & 63) == 0) sw[threadIdx.x >> 6] = s;
    __syncthreads();
    if (threadIdx.x == 0)
        res32[a] = sw[0] + sw[1] + sw[2] + sw[3];
}

// Kernel 3: scalar epilogue on the 32 reduced sums.
__global__ __launch_bounds__(64) void bcc_epilogue(
    const float* __restrict__ res32, float invN, float* __restrict__ out)
{
    if (threadIdx.x == 0) {
        const float U  = -res32[30] * invN;          // undistorted_loss
        const float vd =  res32[31] * invN;          // mean variance_depressor
        float mc_sum = 0.0f;
        #pragma unroll
        for (int t = 0; t < TSAMP; ++t) {
            const float D = -res32[t] * invN;        // distorted_loss[t]
            const float x = U - D;
            const float e = (x > 0.0f) ? x : expm1f(x);   // elu(x)
            mc_sum += -e;                             // monte_carlo[t]
        }
        const float variance_loss = (mc_sum / (float)TSAMP) * U;
        out[0] = variance_loss + U + vd;
    }
}

extern "C" void kernel_launch(void* const* d_in, const int* in_sizes, int n_in,
                              void* d_out, int out_size, void* d_ws, size_t ws_size,
                              hipStream_t stream) {
    const float* logit = (const float*)d_in[0];   // [N,2] f32
    const float* var   = (const float*)d_in[1];   // [N,1] f32
    const int*   tru   = (const int*)d_in[2];     // [N]   i32
    const float* noise = (const float*)d_in[3];   // [30,N,2] f32
    float* out = (float*)d_out;

    const int N = in_sizes[1];          // var has N elements
    const int npair = N / 2;

    int npr = (npair + RPB - 1) / RPB;  // 256 for N=1M
    {
        const size_t need = (size_t)32 * (size_t)npr * sizeof(float) + 32 * sizeof(float);
        if (ws_size < need) {
            npr = (int)((ws_size - 32 * sizeof(float)) / (32 * sizeof(float)));
            if (npr < 1) npr = 1;
        }
    }
    float* partial = (float*)d_ws;                       // [32][npr]
    float* res32   = partial + (size_t)32 * (size_t)npr; // [32]

    bcc_partial<<<TSAMP * npr, 256, 0, stream>>>(
        (const float4*)logit, (const float2*)var, (const int2*)tru,
        (const float4*)noise, partial, npair, npr);

    bcc_reduce<<<32, 256, 0, stream>>>(partial, npr, res32);

    bcc_epilogue<<<1, 64, 0, stream>>>(res32, 1.0f / (float)N, out);
}